// Round 1
// baseline (11.226 us; speedup 1.0000x reference)
//
#include <hip/hip_runtime.h>
#include <math.h>

// Fused Net_6maxFull: gen-LSTM (10 cells, H=10) + game-LSTM (5x10 cells, H=5)
// + masked average + 3-layer tanh MLP. Single block, everything in LDS.

__device__ __forceinline__ float sigf(float v) {
    return 1.0f / (1.0f + expf(-v));
}

__global__ __launch_bounds__(256) void net6max_kernel(
    const float* __restrict__ x,        // [37]
    const float* __restrict__ gen_Wih,  // [10][40][12]
    const float* __restrict__ gen_Whh,  // [10][40][10]
    const float* __restrict__ gen_bih,  // [10][40]
    const float* __restrict__ gen_bhh,  // [10][40]
    const float* __restrict__ gen_h0,   // [10][10]
    const float* __restrict__ gen_c0,   // [10][10]
    const float* __restrict__ game_Wih, // [5][10][20][4]
    const float* __restrict__ game_Whh, // [5][10][20][5]
    const float* __restrict__ game_bih, // [5][10][20]
    const float* __restrict__ game_bhh, // [5][10][20]
    const float* __restrict__ game_h0,  // [5][10][5]
    const float* __restrict__ game_c0,  // [5][10][5]
    const float* __restrict__ W1,       // [50][200]
    const float* __restrict__ b1,       // [50]
    const float* __restrict__ W2,       // [10][50]
    const float* __restrict__ b2,       // [10]
    const float* __restrict__ W3,       // [1][10]
    const float* __restrict__ b3,       // [1]
    float* __restrict__ out)            // [1]
{
    __shared__ float s_xg[12];
    __shared__ float s_feats[5][4];
    __shared__ float s_active[5];
    __shared__ float s_gates_g[10][40];
    __shared__ float s_gates_o[5][10][20];
    __shared__ float s_hgame[5][10][5];
    __shared__ float s_test[200];
    __shared__ float s_h1[50];
    __shared__ float s_h2[10];

    const int tid = threadIdx.x;

    // ---- stage x slices into LDS ----
    if (tid < 12) s_xg[tid] = x[tid];
    if (tid >= 32 && tid < 32 + 25) {
        int j = tid - 32;           // 0..24 -> xo[5][5]
        int o = j / 5, c = j % 5;
        float v = x[12 + j];
        if (c == 0) s_active[o] = v;
        else        s_feats[o][c - 1] = v;
    }
    __syncthreads();

    // ---- gen gates: 400 gates, 22 MACs each ----
    for (int idx = tid; idx < 400; idx += 256) {
        int k = idx / 40, g = idx % 40;
        const float* wih = gen_Wih + (size_t)(k * 40 + g) * 12;
        const float* whh = gen_Whh + (size_t)(k * 40 + g) * 10;
        const float* h0  = gen_h0 + k * 10;
        float acc = gen_bih[idx] + gen_bhh[idx];
        #pragma unroll
        for (int d = 0; d < 12; ++d) acc += wih[d] * s_xg[d];
        #pragma unroll
        for (int h = 0; h < 10; ++h) acc += whh[h] * h0[h];
        s_gates_g[k][g] = acc;
    }

    // ---- game gates: 1000 gates, 9 MACs each ----
    for (int idx = tid; idx < 1000; idx += 256) {
        int o = idx / 200;
        int rem = idx % 200;
        int k = rem / 20, g = rem % 20;
        const float* wih = game_Wih + (size_t)((o * 10 + k) * 20 + g) * 4;
        const float* whh = game_Whh + (size_t)((o * 10 + k) * 20 + g) * 5;
        const float* h0  = game_h0 + (o * 10 + k) * 5;
        float acc = game_bih[idx] + game_bhh[idx];
        #pragma unroll
        for (int d = 0; d < 4; ++d) acc += wih[d] * s_feats[o][d];
        #pragma unroll
        for (int h = 0; h < 5; ++h) acc += whh[h] * h0[h];
        s_gates_o[o][k][g] = acc;
    }
    __syncthreads();

    // ---- gen LSTM cell -> test[0..99] (h_gen flattened) ----
    if (tid < 100) {
        int k = tid / 10, j = tid % 10;
        float gi = s_gates_g[k][j];
        float gf = s_gates_g[k][10 + j];
        float gg = s_gates_g[k][20 + j];
        float go = s_gates_g[k][30 + j];
        float c = sigf(gf) * gen_c0[k * 10 + j] + sigf(gi) * tanhf(gg);
        s_test[tid] = sigf(go) * tanhf(c);
    }
    // ---- game LSTM cell -> s_hgame[5][10][5] ----
    if (tid < 250) {
        int o = tid / 50;
        int rem = tid % 50;
        int k = rem / 5, j = rem % 5;
        float gi = s_gates_o[o][k][j];
        float gf = s_gates_o[o][k][5 + j];
        float gg = s_gates_o[o][k][10 + j];
        float go = s_gates_o[o][k][15 + j];
        float c = sigf(gf) * game_c0[(o * 10 + k) * 5 + j] + sigf(gi) * tanhf(gg);
        s_hgame[o][k][j] = sigf(go) * tanhf(c);
    }
    __syncthreads();

    // ---- masked average over active opponents -> test[100..199] ----
    if (tid < 100) {
        float msum = 0.0f, acc = 0.0f;
        #pragma unroll
        for (int o = 0; o < 5; ++o) {
            float m = (s_active[o] == 1.0f) ? 1.0f : 0.0f;
            msum += m;
            float v = (tid < 50) ? s_hgame[o][tid / 5][tid % 5]
                                 : s_hgame[o][9][(tid - 50) % 5];
            acc += m * v;
        }
        s_test[100 + tid] = acc / msum;
    }
    __syncthreads();

    // ---- MLP layer 1: [50] = tanh(W1[50][200] @ test + b1) ----
    if (tid < 50) {
        const float* w = W1 + (size_t)tid * 200;
        float acc = b1[tid];
        for (int c = 0; c < 200; ++c) acc += w[c] * s_test[c];
        s_h1[tid] = tanhf(acc);
    }
    __syncthreads();

    // ---- MLP layer 2: [10] = tanh(W2[10][50] @ h1 + b2) ----
    if (tid < 10) {
        const float* w = W2 + (size_t)tid * 50;
        float acc = b2[tid];
        #pragma unroll
        for (int c = 0; c < 50; ++c) acc += w[c] * s_h1[c];
        s_h2[tid] = tanhf(acc);
    }
    __syncthreads();

    // ---- MLP layer 3: scalar ----
    if (tid == 0) {
        float acc = b3[0];
        #pragma unroll
        for (int c = 0; c < 10; ++c) acc += W3[c] * s_h2[c];
        out[0] = tanhf(acc);
    }
}

extern "C" void kernel_launch(void* const* d_in, const int* in_sizes, int n_in,
                              void* d_out, int out_size, void* d_ws, size_t ws_size,
                              hipStream_t stream) {
    (void)in_sizes; (void)n_in; (void)out_size; (void)d_ws; (void)ws_size;
    const float* x        = (const float*)d_in[0];
    const float* gen_Wih  = (const float*)d_in[1];
    const float* gen_Whh  = (const float*)d_in[2];
    const float* gen_bih  = (const float*)d_in[3];
    const float* gen_bhh  = (const float*)d_in[4];
    const float* gen_h0   = (const float*)d_in[5];
    const float* gen_c0   = (const float*)d_in[6];
    const float* game_Wih = (const float*)d_in[7];
    const float* game_Whh = (const float*)d_in[8];
    const float* game_bih = (const float*)d_in[9];
    const float* game_bhh = (const float*)d_in[10];
    const float* game_h0  = (const float*)d_in[11];
    const float* game_c0  = (const float*)d_in[12];
    const float* W1       = (const float*)d_in[13];
    const float* b1       = (const float*)d_in[14];
    const float* W2       = (const float*)d_in[15];
    const float* b2       = (const float*)d_in[16];
    const float* W3       = (const float*)d_in[17];
    const float* b3       = (const float*)d_in[18];
    float* out = (float*)d_out;

    net6max_kernel<<<1, 256, 0, stream>>>(
        x, gen_Wih, gen_Whh, gen_bih, gen_bhh, gen_h0, gen_c0,
        game_Wih, game_Whh, game_bih, game_bhh, game_h0, game_c0,
        W1, b1, W2, b2, W3, b3, out);
}

// Round 2
// 9.469 us; speedup vs baseline: 1.1855x; 1.1855x over previous
//
#include <hip/hip_runtime.h>
#include <math.h>

// Fused Net_6maxFull: gen-LSTM (10 cells, H=10) + game-LSTM (5x10 cells, H=5)
// + masked average + 3-layer tanh MLP. Single block of 1024 threads, one task
// per thread per phase, everything staged in LDS, fast transcendentals.

__device__ __forceinline__ float fsig(float v) {
    // 1/(1+e^-v) via hardware exp; |err| ~1e-6, threshold is 7.2e-4
    return __fdividef(1.0f, 1.0f + __expf(-v));
}
__device__ __forceinline__ float ftanh(float v) {
    // tanh(v) = 1 - 2/(1+e^{2v}); saturates correctly for |v| large
    return 1.0f - __fdividef(2.0f, 1.0f + __expf(2.0f * v));
}

__global__ __launch_bounds__(1024) void net6max_kernel(
    const float* __restrict__ x,        // [37]
    const float* __restrict__ gen_Wih,  // [10][40][12]
    const float* __restrict__ gen_Whh,  // [10][40][10]
    const float* __restrict__ gen_bih,  // [10][40]
    const float* __restrict__ gen_bhh,  // [10][40]
    const float* __restrict__ gen_h0,   // [10][10]
    const float* __restrict__ gen_c0,   // [10][10]
    const float* __restrict__ game_Wih, // [5][10][20][4]
    const float* __restrict__ game_Whh, // [5][10][20][5]
    const float* __restrict__ game_bih, // [5][10][20]
    const float* __restrict__ game_bhh, // [5][10][20]
    const float* __restrict__ game_h0,  // [5][10][5]
    const float* __restrict__ game_c0,  // [5][10][5]
    const float* __restrict__ W1,       // [50][200]
    const float* __restrict__ b1,       // [50]
    const float* __restrict__ W2,       // [10][50]
    const float* __restrict__ b2,       // [10]
    const float* __restrict__ W3,       // [1][10]
    const float* __restrict__ b3,       // [1]
    float* __restrict__ out)            // [1]
{
    __shared__ __align__(16) float s_xg[12];
    __shared__ __align__(16) float s_feats[5][4];
    __shared__ __align__(16) float s_active[8];
    __shared__ __align__(16) float s_gates_g[400];
    __shared__ __align__(16) float s_gates_o[1000];
    __shared__ __align__(16) float s_hgame[5][10][5];
    __shared__ __align__(16) float s_test[200];
    __shared__ __align__(16) float s_h1[52];
    __shared__ __align__(16) float s_h2[12];

    const int tid = threadIdx.x;

    // ---- stage x slices into LDS (two different waves) ----
    if (tid < 12) s_xg[tid] = x[tid];
    if (tid >= 64 && tid < 64 + 25) {
        int j = tid - 64;           // 0..24 -> xo[5][5]
        int o = j / 5, c = j % 5;
        float v = x[12 + j];
        if (c == 0) s_active[o] = v;
        else        s_feats[o][c - 1] = v;
    }
    __syncthreads();

    // ---- gen gates: 400 gates, one per thread, vectorized loads ----
    if (tid < 400) {
        int k = tid / 40;
        const float4* wih4 = (const float4*)(gen_Wih + (size_t)tid * 12);
        const float2* whh2 = (const float2*)(gen_Whh + (size_t)tid * 10);
        const float2* h02  = (const float2*)(gen_h0 + k * 10);
        float4 xa = *(const float4*)&s_xg[0];
        float4 xb = *(const float4*)&s_xg[4];
        float4 xc = *(const float4*)&s_xg[8];
        float4 p4 = wih4[0] * xa + wih4[1] * xb + wih4[2] * xc;
        float2 q2 = whh2[0] * h02[0] + whh2[1] * h02[1] + whh2[2] * h02[2]
                  + whh2[3] * h02[3] + whh2[4] * h02[4];
        float acc = gen_bih[tid] + gen_bhh[tid]
                  + p4.x + p4.y + p4.z + p4.w + q2.x + q2.y;
        s_gates_g[tid] = acc;
    }

    // ---- game gates: 1000 gates, exactly-once mapping over 1024 threads ----
    {
        int gt = -1;
        if (tid < 400)       gt = 600 + tid;     // tasks 600..999
        else if (tid >= 424) gt = tid - 424;     // tasks 0..599
        if (gt >= 0) {
            int o   = gt / 200;
            int ok_ = gt / 20;                   // o*10 + k
            const float4* wih4 = (const float4*)(game_Wih + (size_t)gt * 4);
            const float*  whh  = game_Whh + (size_t)gt * 5;
            const float*  h0   = game_h0 + ok_ * 5;
            float4 f4 = *(const float4*)&s_feats[o][0];
            float4 p  = wih4[0] * f4;
            float acc = game_bih[gt] + game_bhh[gt] + p.x + p.y + p.z + p.w;
            acc += whh[0]*h0[0] + whh[1]*h0[1] + whh[2]*h0[2]
                 + whh[3]*h0[3] + whh[4]*h0[4];
            s_gates_o[gt] = acc;
        }
    }
    __syncthreads();

    // ---- LSTM nonlinearities: gen on waves 0-1, game on waves 8-11 ----
    if (tid < 100) {
        int k = tid / 10, j = tid % 10;
        int base = k * 40;
        float gi = s_gates_g[base + j];
        float gf = s_gates_g[base + 10 + j];
        float gg = s_gates_g[base + 20 + j];
        float go = s_gates_g[base + 30 + j];
        float c = fsig(gf) * gen_c0[tid] + fsig(gi) * ftanh(gg);
        s_test[tid] = fsig(go) * ftanh(c);
    } else if (tid >= 512 && tid < 512 + 250) {
        int t = tid - 512;
        int o = t / 50;
        int rem = t % 50;
        int k = rem / 5, j = rem % 5;
        int base = (o * 10 + k) * 20;
        float gi = s_gates_o[base + j];
        float gf = s_gates_o[base + 5 + j];
        float gg = s_gates_o[base + 10 + j];
        float go = s_gates_o[base + 15 + j];
        float c = fsig(gf) * game_c0[(o * 10 + k) * 5 + j] + fsig(gi) * ftanh(gg);
        s_hgame[o][k][j] = fsig(go) * ftanh(c);
    }
    __syncthreads();

    // ---- masked average over active opponents -> test[100..199] ----
    if (tid < 100) {
        float msum = 0.0f, acc = 0.0f;
        #pragma unroll
        for (int o = 0; o < 5; ++o) {
            float m = (s_active[o] == 1.0f) ? 1.0f : 0.0f;
            msum += m;
            float v = (tid < 50) ? s_hgame[o][tid / 5][tid % 5]
                                 : s_hgame[o][9][(tid - 50) % 5];
            acc += m * v;
        }
        s_test[100 + tid] = __fdividef(acc, msum);
    }
    __syncthreads();

    // ---- MLP layer 1: 50 rows x 200 cols, 4 threads/row, float4 MACs ----
    if (tid < 200) {
        int r = tid >> 2, q = tid & 3;
        const float4* w4 = (const float4*)(W1 + (size_t)r * 200);
        const float4* t4 = (const float4*)s_test;
        float4 acc4 = make_float4(0.f, 0.f, 0.f, 0.f);
        #pragma unroll
        for (int m = 0; m < 12; ++m) {
            int c4 = q + 4 * m;          // float4-index; disjoint across quad
            acc4 += w4[c4] * t4[c4];
        }
        if (q < 2) {                      // tail cols 192..199
            int c4 = 48 + q;
            acc4 += w4[c4] * t4[c4];
        }
        float acc = acc4.x + acc4.y + acc4.z + acc4.w;
        acc += __shfl_xor(acc, 1);
        acc += __shfl_xor(acc, 2);
        if (q == 0) s_h1[r] = ftanh(acc + b1[r]);
    }
    __syncthreads();

    // ---- MLP layer 2: 10 rows x 50 cols, 2 threads/row, float2 MACs ----
    if (tid < 20) {
        int r = tid >> 1, q = tid & 1;
        const float2* w2 = (const float2*)(W2 + (size_t)r * 50);
        const float2* h2 = (const float2*)s_h1;
        float2 acc2 = make_float2(0.f, 0.f);
        #pragma unroll
        for (int m = 0; m < 12; ++m) {
            int c = q + 2 * m;
            acc2 += w2[c] * h2[c];
        }
        if (q == 0) acc2 += w2[24] * h2[24];
        float acc = acc2.x + acc2.y;
        acc += __shfl_xor(acc, 1);
        if (q == 0) s_h2[r] = ftanh(acc + b2[r]);
    }
    __syncthreads();

    // ---- MLP layer 3: scalar ----
    if (tid == 0) {
        float acc = b3[0];
        #pragma unroll
        for (int c = 0; c < 10; ++c) acc += W3[c] * s_h2[c];
        out[0] = ftanh(acc);
    }
}

extern "C" void kernel_launch(void* const* d_in, const int* in_sizes, int n_in,
                              void* d_out, int out_size, void* d_ws, size_t ws_size,
                              hipStream_t stream) {
    (void)in_sizes; (void)n_in; (void)out_size; (void)d_ws; (void)ws_size;
    const float* x        = (const float*)d_in[0];
    const float* gen_Wih  = (const float*)d_in[1];
    const float* gen_Whh  = (const float*)d_in[2];
    const float* gen_bih  = (const float*)d_in[3];
    const float* gen_bhh  = (const float*)d_in[4];
    const float* gen_h0   = (const float*)d_in[5];
    const float* gen_c0   = (const float*)d_in[6];
    const float* game_Wih = (const float*)d_in[7];
    const float* game_Whh = (const float*)d_in[8];
    const float* game_bih = (const float*)d_in[9];
    const float* game_bhh = (const float*)d_in[10];
    const float* game_h0  = (const float*)d_in[11];
    const float* game_c0  = (const float*)d_in[12];
    const float* W1       = (const float*)d_in[13];
    const float* b1       = (const float*)d_in[14];
    const float* W2       = (const float*)d_in[15];
    const float* b2       = (const float*)d_in[16];
    const float* W3       = (const float*)d_in[17];
    const float* b3       = (const float*)d_in[18];
    float* out = (float*)d_out;

    net6max_kernel<<<1, 1024, 0, stream>>>(
        x, gen_Wih, gen_Whh, gen_bih, gen_bhh, gen_h0, gen_c0,
        game_Wih, game_Whh, game_bih, game_bhh, game_h0, game_c0,
        W1, b1, W2, b2, W3, b3, out);
}